// Round 1
// 1281.567 us; speedup vs baseline: 1.0883x; 1.0883x over previous
//
#include <hip/hip_runtime.h>

#define AG __HIP_MEMORY_SCOPE_AGENT
#define B_ 16
#define T_ 512
#define P_ 2048
#define SN_ 256
#define SD_ 1024
#define NGD 8                 // den groups (one b-pair each)
#define GB 16                 // blocks per den group (64 cols each)
#define NBD (NGD * GB)        // 128 den blocks
#define NBLK (NBD + B_)       // + 16 num blocks = 144
#define NTHR 1024
#define CHU 136               // chunk stride in u64 (64 b0 + 64 b1 + 2 M + pad)

typedef unsigned long long u64;

__device__ __forceinline__ float alf(const float* p){ return __hip_atomic_load(p, __ATOMIC_RELAXED, AG); }
__device__ __forceinline__ void  asf(float* p, float v){ __hip_atomic_store(p, v, __ATOMIC_RELAXED, AG); }
__device__ __forceinline__ void  rsu(unsigned* p, unsigned v){ __hip_atomic_store(p, v, __ATOMIC_RELEASE, AG); }
__device__ __forceinline__ u64   ald64(const u64* p){ return __hip_atomic_load(p, __ATOMIC_RELAXED, AG); }
__device__ __forceinline__ void  ast64(u64* p, u64 v){ __hip_atomic_store(p, v, __ATOMIC_RELAXED, AG); }
__device__ __forceinline__ u64   pk(float v, unsigned t){ return ((u64)t << 32) | (u64)__float_as_uint(v); }
__device__ __forceinline__ void wait_eq(unsigned* p, unsigned v){
  while (__hip_atomic_load(p, __ATOMIC_RELAXED, AG) != v) __builtin_amdgcn_s_sleep(1);
  asm volatile("" ::: "memory");
}

// Exp-space forward recursion, producer/consumer dataflow, ONE barrier/step:
//   q_t[b,c] = (sum_k q_{t-1}[b,k] * W[k,c]) / M[b] * exp(e_t[b,c])
// den: 8 groups x 16 blocks; group owns b-pair {2g,2g+1}; block owns 64 cols.
// Step: wave wv polls its producer's tagged chunk into PRIVATE LDS scratch
// (same-wave write->read: lgkmcnt only, no barrier), computes partials for
// all 128 outputs over its k-slice-64 (W in 64 regs), writes red[parity].
// ONE __syncthreads. Then 8-lane teams fold one output each (2 LDS reads +
// 3 shuffles); team lead publishes its tagged word directly.
// ROUND 10: stage-phase polls are issued in PARALLEL (q0, q1, and wave0's
// Ms words) instead of chained poll_tag calls — the serial version cost
// 2-3 full LLC round trips per step, and wave0's third poll gated the
// block barrier every step. Dataflow/tags/numerics unchanged.
// Frozen carry kept in lead's REGISTER (v_prev). 2-parity red/Ms: a wave at
// sync(t+1) implies all waves finished fold(t), so parity-(t&1) is only
// rewritten at t+2 — race-free with a single barrier.
// M = 8-col max (r0 wave0/wave8 teams) — any fixed-subset scale is valid
// (self-correcting, within-step spread bounded, fp32 range huge).
// num: fully block-local, W in registers, 16 independent blocks.
__global__ void __attribute__((amdgpu_flat_work_group_size(1024, 1024)))
__attribute__((amdgpu_waves_per_eu(4, 4))) lfmmi_kernel(
    const float* __restrict__ input, const int* __restrict__ seqlen,
    const float* __restrict__ num_init, const float* __restrict__ num_trans,
    const float* __restrict__ num_final, const int* __restrict__ num_pdf,
    const float* __restrict__ den_init, const float* __restrict__ den_trans,
    const float* __restrict__ den_final, const int* __restrict__ den_pdf,
    float* __restrict__ out, float* __restrict__ ws)
{
  __shared__ __align__(16) unsigned char smem[25248];
  const int tid = threadIdx.x;
  const int bid = blockIdx.x;

  // workspace carve
  u64*      Qc     = (u64*)ws;                         // [2][NGD][GB][CHU]
  float*    DenRes = (float*)(Qc + 2*NGD*GB*CHU);      // [16]
  float*    NumRes = DenRes + 16;                      // [16]
  unsigned* DF     = (unsigned*)(NumRes + 16);         // [NGD][16]
  unsigned* NF     = DF + NGD*16;                      // [16][16]

  const int wv = tid >> 6, ln = tid & 63;

  if (bid < NBD) {
    // ================= DEN =================
    const int g = bid >> 4, r = bid & 15;
    const int col0 = r * 64;
    const int tm = ln >> 3, j8 = ln & 7;     // team, lane-in-team
    const int o  = 8 * wv + tm;              // output index this team folds
    const int ob = o >> 6, oc = o & 63;      // batch-half, column of output
    const bool lead = (j8 == 0);

    float* qsW = (float*)smem;               // [16][136] per-wave scratch
    float* red = (float*)(smem + 8704);      // [2][16][129] partials
    float* Ms  = (float*)(smem + 25216);     // [2][2] (parity, b)

    // --- W regs: wreg[j] = exp(trans[64*wv + j][col0 + ln]) ---
    float wreg[64];
    {
      const float* wb = den_trans + (size_t)(64 * wv) * SD_ + col0 + ln;
      #pragma unroll
      for (int j = 0; j < 64; ++j) wreg[j] = __expf(wb[(size_t)j * SD_]);
    }

    const int b0 = 2 * g, b1 = 2 * g + 1;
    const size_t inb0 = (size_t)b0 * T_ * P_, inb1 = (size_t)b1 * T_ * P_;
    int pdfc = 0, slenL = 0; size_t inbL = 0;
    if (lead) {
      pdfc  = den_pdf[col0 + oc];
      inbL  = ob ? inb1 : inb0;
      slenL = seqlen[ob ? b1 : b0];
    }
    u64* myCh0 = Qc + ((size_t)(0 * NGD + g) * GB + r) * CHU;
    u64* myCh1 = Qc + ((size_t)(1 * NGD + g) * GB + r) * CHU;

    // --- init: every team lead computes + publishes its own q0 (tag 0) ---
    float v_prev = 0.f, Lr = 0.f;
    if (lead) {
      v_prev = __expf(den_init[col0 + oc] + input[inbL + pdfc]);
      ast64(myCh0 + o, pk(v_prev, 0u));
    }
    if (r == 0 && (wv == 0 || wv == 8)) {     // M0 from wave0 (b0), M1 from wave8 (b1)
      float mx = lead ? v_prev : 0.f;
      #pragma unroll
      for (int d = 1; d < 64; d <<= 1) mx = fmaxf(mx, __shfl_xor(mx, d));
      if (ln == 0) ast64(myCh0 + 128 + ob, pk(mx, 0u));
    }

    for (int t = 1; t <= 511; ++t) {
      const int pp = (t - 1) & 1, pc = t & 1;
      const unsigned et = (unsigned)(t - 1);
      // lead: prefetch emission gather (hidden behind the poll)
      float e = 0.f;
      if (lead) e = input[inbL + (size_t)t * P_ + pdfc];

      // stage: wave wv polls its producer's chunk into private scratch.
      // ALL poll loads issued in parallel before any wait; retry only
      // stale streams. (Serial poll_tag chained 2-3 LLC round trips.)
      {
        const u64* chs = Qc + ((size_t)(pp * NGD + g) * GB + wv) * CHU;
        const u64* p0 = chs + ln;
        const u64* p1 = chs + 64 + ln;
        const bool pm = (wv == 0 && ln < 2);
        const u64* p2 = chs + 128 + ln;     // only dereferenced when pm
        u64 x0 = ald64(p0);
        u64 x1 = ald64(p1);
        u64 x2 = pm ? ald64(p2) : 0;
        while ((unsigned)(x0 >> 32) != et) x0 = ald64(p0);
        qsW[wv * 136 + ln] = __uint_as_float((unsigned)x0);
        while ((unsigned)(x1 >> 32) != et) x1 = ald64(p1);
        qsW[wv * 136 + 64 + ln] = __uint_as_float((unsigned)x1);
        if (pm) {
          while ((unsigned)(x2 >> 32) != et) x2 = ald64(p2);
          Ms[pp * 2 + ln] = __uint_as_float((unsigned)x2);
        }
      }
      // compute partials for all 128 outputs over own k-slice (broadcast reads)
      float a0 = 0.f, a1 = 0.f;
      {
        const float* qp = qsW + wv * 136;
        #pragma unroll
        for (int jj = 0; jj < 16; ++jj) {
          const float4 f0 = *(const float4*)(qp + 4 * jj);
          const float4 f1 = *(const float4*)(qp + 64 + 4 * jj);
          a0 = fmaf(f0.x, wreg[4*jj+0], a0); a0 = fmaf(f0.y, wreg[4*jj+1], a0);
          a0 = fmaf(f0.z, wreg[4*jj+2], a0); a0 = fmaf(f0.w, wreg[4*jj+3], a0);
          a1 = fmaf(f1.x, wreg[4*jj+0], a1); a1 = fmaf(f1.y, wreg[4*jj+1], a1);
          a1 = fmaf(f1.z, wreg[4*jj+2], a1); a1 = fmaf(f1.w, wreg[4*jj+3], a1);
        }
      }
      red[(pc * 16 + wv) * 129 + ln]      = a0;   // output o=ln   (b0)
      red[(pc * 16 + wv) * 129 + 64 + ln] = a1;   // output o=64+ln (b1)
      __syncthreads();   // the ONLY barrier per step

      // fold: team folds output o; lead scales + publishes
      float acc = red[(pc * 16 + 2 * j8) * 129 + o]
                + red[(pc * 16 + 2 * j8 + 1) * 129 + o];
      acc += __shfl_xor(acc, 1);
      acc += __shfl_xor(acc, 2);
      acc += __shfl_xor(acc, 4);
      u64* myCh = pc ? myCh1 : myCh0;
      if (lead) {
        const float Mv = Ms[pp * 2 + ob];
        if (t < slenL) v_prev = (acc / Mv) * __expf(e);   // else frozen carry
        ast64(myCh + o, pk(v_prev, (unsigned)t));
      }
      if (r == 0 && (wv == 0 || wv == 8)) {
        float mx = lead ? v_prev : 0.f;
        #pragma unroll
        for (int d = 1; d < 64; d <<= 1) mx = fmaxf(mx, __shfl_xor(mx, d));
        if (ln == 0) {
          ast64(myCh + 128 + ob, pk(mx, (unsigned)t));
          if (t < slenL) Lr += __logf(Ms[pp * 2 + ob]);   // lane0: lead of o=0/64
        }
      }
    }

    // --- epilogue: r==0 blocks reduce final q (t=511, parity 1) ---
    if (r == 0) {
      __syncthreads();
      float* qf = (float*)smem;               // [2][1024]
      float* rs = (float*)(smem + 8192);      // [1024] x2 halves (ends 16384 < red[1] base)
      {
        const u64* ch = Qc + ((size_t)(1 * NGD + g) * GB + wv) * CHU;
        const u64* p0 = ch + ln;
        const u64* p1 = ch + 64 + ln;
        u64 y0 = ald64(p0);
        u64 y1 = ald64(p1);
        while ((unsigned)(y0 >> 32) != 511u) y0 = ald64(p0);
        while ((unsigned)(y1 >> 32) != 511u) y1 = ald64(p1);
        qf[wv * 64 + ln]        = __uint_as_float((unsigned)y0);
        qf[1024 + wv * 64 + ln] = __uint_as_float((unsigned)y1);
      }
      __syncthreads();
      const int b2e = tid >> 9, ce = tid & 511;
      rs[tid] = qf[b2e * 1024 + ce] * __expf(den_final[ce])
              + qf[b2e * 1024 + 512 + ce] * __expf(den_final[512 + ce]);
      __syncthreads();
      for (int off = 256; off; off >>= 1) {
        const int base = (tid >= 512) ? 512 : 0, i = tid - base;
        if (i < off) rs[base + i] += rs[base + i + off];
        __syncthreads();
      }
      if (tid == 0)   asf(DenRes + 2 * g,     Lr + __logf(rs[0]));     // wave0 lane0: Lr(b0)
      if (tid == 512) asf(DenRes + 2 * g + 1, Lr + __logf(rs[512]));   // wave8 lane0: Lr(b1)
      __syncthreads();
      if (tid == 0) {
        rsu(DF + g * 16, 0x600D0000u | (unsigned)g);
        if (g == 0) {
          for (int g2 = 0; g2 < NGD; ++g2) wait_eq(DF + g2 * 16, 0x600D0000u | (unsigned)g2);
          for (int b2 = 0; b2 < B_; ++b2)  wait_eq(NF + b2 * 16, 0x600D0100u | (unsigned)b2);
          float sden = 0.f, snum = 0.f;
          for (int i = 0; i < 16; ++i) { sden += alf(DenRes + i); snum += alf(NumRes + i); }
          out[0] = -(snum - sden);
        }
      }
    }
  } else {
    // ================= NUM (fully block-local, unchanged) =================
    const int b = bid - NBD;
    float* qn   = (float*)smem;               // [2][256] 2 KB
    float* redn = (float*)(smem + 2048);      // [16][256] 16 KB
    float* Ms2  = (float*)(smem + 18432);     // [2]
    const size_t inb = (size_t)b * T_ * P_;
    const int slen = seqlen[b];

    float wn[64];
    {
      const float* wb = num_trans + (size_t)(wv * 16) * SN_ + ln;
      #pragma unroll
      for (int kk = 0; kk < 16; ++kk) {
        #pragma unroll
        for (int cc = 0; cc < 4; ++cc)
          wn[kk * 4 + cc] = __expf(wb[(size_t)kk * SN_ + 64 * cc]);
      }
    }
    int pdfn[4] = {0, 0, 0, 0};
    float Lr = 0.f;
    if (wv == 0) {
      #pragma unroll
      for (int cc = 0; cc < 4; ++cc) pdfn[cc] = num_pdf[ln + 64 * cc];
      float mx = 0.f;
      #pragma unroll
      for (int cc = 0; cc < 4; ++cc) {
        const float v = __expf(num_init[ln + 64 * cc] + input[inb + pdfn[cc]]);
        qn[ln + 64 * cc] = v;
        mx = fmaxf(mx, v);
      }
      #pragma unroll
      for (int d = 1; d < 64; d <<= 1) mx = fmaxf(mx, __shfl_xor(mx, d));
      if (ln == 0) Ms2[0] = mx;
    }
    __syncthreads();

    int tlast = 0;
    for (int t = 1; t <= 511; ++t) {
      if (t >= slen) break;
      tlast = t;
      const int pr = (t - 1) & 1, pw = t & 1;
      float e[4] = {0.f, 0.f, 0.f, 0.f};
      if (wv == 0) {
        #pragma unroll
        for (int cc = 0; cc < 4; ++cc) e[cc] = input[inb + (size_t)t * P_ + pdfn[cc]];
      }
      const float* qp = qn + pr * 256 + wv * 16;
      float ac[4] = {0.f, 0.f, 0.f, 0.f};
      #pragma unroll
      for (int jj = 0; jj < 4; ++jj) {
        const float4 f = *(const float4*)(qp + 4 * jj);
        #pragma unroll
        for (int cc = 0; cc < 4; ++cc) {
          ac[cc] = fmaf(f.x, wn[(4*jj+0)*4+cc], ac[cc]);
          ac[cc] = fmaf(f.y, wn[(4*jj+1)*4+cc], ac[cc]);
          ac[cc] = fmaf(f.z, wn[(4*jj+2)*4+cc], ac[cc]);
          ac[cc] = fmaf(f.w, wn[(4*jj+3)*4+cc], ac[cc]);
        }
      }
      #pragma unroll
      for (int cc = 0; cc < 4; ++cc) redn[wv * 256 + cc * 64 + ln] = ac[cc];
      __syncthreads();
      if (wv == 0) {
        float acc[4] = {0.f, 0.f, 0.f, 0.f};
        #pragma unroll
        for (int w = 0; w < 16; ++w) {
          #pragma unroll
          for (int cc = 0; cc < 4; ++cc) acc[cc] += redn[w * 256 + cc * 64 + ln];
        }
        const float Mv = Ms2[pr];
        const float rM = 1.0f / Mv;
        float mx = 0.f;
        #pragma unroll
        for (int cc = 0; cc < 4; ++cc) {
          const float v = acc[cc] * rM * __expf(e[cc]);
          qn[pw * 256 + ln + 64 * cc] = v;
          mx = fmaxf(mx, v);
        }
        #pragma unroll
        for (int d = 1; d < 64; d <<= 1) mx = fmaxf(mx, __shfl_xor(mx, d));
        if (ln == 0) { Ms2[pw] = mx; Lr += __logf(Mv); }
      }
      __syncthreads();
    }
    const int cur = tlast & 1;
    if (wv == 0) {
      float s = 0.f;
      #pragma unroll
      for (int cc = 0; cc < 4; ++cc)
        s += qn[cur * 256 + ln + 64 * cc] * __expf(num_final[ln + 64 * cc]);
      #pragma unroll
      for (int d = 1; d < 64; d <<= 1) s += __shfl_xor(s, d);
      if (ln == 0) {
        asf(NumRes + b, Lr + __logf(s));
        rsu(NF + b * 16, 0x600D0100u | (unsigned)b);
      }
    }
  }
}

extern "C" void kernel_launch(void* const* d_in, const int* in_sizes, int n_in,
                              void* d_out, int out_size, void* d_ws, size_t ws_size,
                              hipStream_t stream) {
  const float* input     = (const float*)d_in[0];
  const int*   seqlen    = (const int*)  d_in[1];
  const float* num_init  = (const float*)d_in[2];
  const float* num_trans = (const float*)d_in[3];
  const float* num_final = (const float*)d_in[4];
  const int*   num_pdf   = (const int*)  d_in[5];
  const float* den_init  = (const float*)d_in[6];
  const float* den_trans = (const float*)d_in[7];
  const float* den_final = (const float*)d_in[8];
  const int*   den_pdf   = (const int*)  d_in[9];
  float* out = (float*)d_out;
  float* ws  = (float*)d_ws;   // ~280 KB used (tagged chunks + results + flags)

  void* args[] = { &input, &seqlen, &num_init, &num_trans, &num_final, &num_pdf,
                   &den_init, &den_trans, &den_final, &den_pdf, &out, &ws };
  hipLaunchCooperativeKernel((void*)lfmmi_kernel, dim3(NBLK), dim3(NTHR),
                             args, 0, stream);
}